// Round 2
// baseline (760.742 us; speedup 1.0000x reference)
//
#include <hip/hip_runtime.h>
#include <hip/hip_bf16.h>

// Fused AllReduce(tp=8 sum) + residual add + RMSNorm, fp32.
// input:    [TP=8, TOKENS=4096, HIDDEN=4096] f32
// residual: [TOKENS, HIDDEN] f32
// weight:   [HIDDEN] f32
// out:      [norm (TOKENS*HIDDEN), hidden_states (TOKENS*HIDDEN)] f32 concat
//
// R2: 1024-thread blocks, one float4/thread, 9 independent loads issued
// before any use (explicit v[] array) -> max memory-level parallelism at
// low VGPR count. One block per token row; block-wide ssq reduction.

constexpr int TP      = 8;
constexpr int TOKENS  = 4096;
constexpr int HIDDEN  = 4096;
constexpr int BLOCK   = 1024;               // 16 waves; HIDDEN/4 float4 = 1024
constexpr int NWAVE   = BLOCK / 64;
constexpr float EPS   = 1e-6f;

__global__ __launch_bounds__(BLOCK)
void fused_ar_rmsnorm(const float* __restrict__ input,
                      const float* __restrict__ residual,
                      const float* __restrict__ weight,
                      float* __restrict__ norm_out,
                      float* __restrict__ hs_out)
{
    const int row = blockIdx.x;
    const size_t row_off = (size_t)row * HIDDEN;
    const int t = threadIdx.x;               // one float4 per thread

    // Issue all 10 independent loads up front (9 data + weight).
    float4 v[TP + 1];
    v[0] = ((const float4*)(residual + row_off))[t];
    #pragma unroll
    for (int p = 0; p < TP; ++p) {
        const float4* __restrict__ in4 =
            (const float4*)(input + ((size_t)p * TOKENS + (size_t)row) * HIDDEN);
        v[p + 1] = in4[t];
    }
    const float4 wv = ((const float4*)weight)[t];

    float4 acc = v[0];
    #pragma unroll
    for (int p = 1; p <= TP; ++p) {
        acc.x += v[p].x; acc.y += v[p].y; acc.z += v[p].z; acc.w += v[p].w;
    }

    // Second output: hidden_states
    ((float4*)(hs_out + row_off))[t] = acc;

    float ssq = acc.x * acc.x + acc.y * acc.y + acc.z * acc.z + acc.w * acc.w;

    // Wave64 shuffle reduction, then 16-entry LDS reduction.
    #pragma unroll
    for (int off = 32; off > 0; off >>= 1)
        ssq += __shfl_down(ssq, off, 64);

    __shared__ float red[NWAVE];
    const int wave = t >> 6;
    const int lane = t & 63;
    if (lane == 0) red[wave] = ssq;
    __syncthreads();

    float total = 0.f;
    #pragma unroll
    for (int i = 0; i < NWAVE; ++i) total += red[i];   // same-addr LDS broadcast

    const float inv = rsqrtf(total * (1.0f / HIDDEN) + EPS);

    float4 o;
    o.x = acc.x * inv * wv.x;
    o.y = acc.y * inv * wv.y;
    o.z = acc.z * inv * wv.z;
    o.w = acc.w * inv * wv.w;
    ((float4*)(norm_out + row_off))[t] = o;
}

extern "C" void kernel_launch(void* const* d_in, const int* in_sizes, int n_in,
                              void* d_out, int out_size, void* d_ws, size_t ws_size,
                              hipStream_t stream) {
    const float* input    = (const float*)d_in[0];
    const float* residual = (const float*)d_in[1];
    const float* weight   = (const float*)d_in[2];
    float* norm_out = (float*)d_out;                       // [TOKENS*HIDDEN]
    float* hs_out   = norm_out + (size_t)TOKENS * HIDDEN;  // [TOKENS*HIDDEN]

    fused_ar_rmsnorm<<<TOKENS, BLOCK, 0, stream>>>(input, residual, weight,
                                                   norm_out, hs_out);
}